// Round 3
// baseline (2547.302 us; speedup 1.0000x reference)
//
#include <hip/hip_runtime.h>
#include <hip/hip_bf16.h>

#define H    2048
#define NI   1408
#define NE   8
#define NTOK 2048
#define NIS  2816

typedef __bf16 bf16x8 __attribute__((ext_vector_type(8)));
typedef float  f32x4  __attribute__((ext_vector_type(4)));

#define ASYNC16(gp, lp) __builtin_amdgcn_global_load_lds( \
    (const __attribute__((address_space(1))) void*)(gp),  \
    (__attribute__((address_space(3))) void*)(lp), 16, 0, 0)

// ---------------------------------------------------------------------------
// Merged convert(+transpose) kernel: one launch for all fp32->bf16 weight prep
// Each 64x64 tile handled by one 256-thread block.
// ---------------------------------------------------------------------------
struct CvtSeg {
    const float* src; __bf16* dst;
    int K, N, ntx, tiles_per_mat, count, trans;
};
struct CvtArgs { CvtSeg s[7]; int base[8]; int nseg; };

__global__ __launch_bounds__(256)
void cvt_all_kernel(CvtArgs a)
{
    const int b = blockIdx.x;
    int si = 0;
    while (si + 1 < a.nseg && b >= a.base[si + 1]) ++si;
    const CvtSeg seg = a.s[si];
    int local = b - a.base[si];
    int mat = local / seg.tiles_per_mat;
    int rem = local - mat * seg.tiles_per_mat;
    int tx = rem % seg.ntx;
    int ty = rem / seg.ntx;
    const float* src = seg.src + (size_t)mat * seg.K * seg.N;
    __bf16*      dst = seg.dst + (size_t)mat * seg.K * seg.N;
    const int n0 = tx * 64, k0 = ty * 64;
    const int t = threadIdx.x;
    const int tr = t >> 4, tc4 = (t & 15) * 4;

    if (!seg.trans) {
#pragma unroll
        for (int i = 0; i < 4; ++i) {
            int k = i * 16 + tr;
            float4 v = *(const float4*)(src + (size_t)(k0 + k) * seg.N + n0 + tc4);
            union { __bf16 h[4]; uint2 u; } p;
            p.h[0] = (__bf16)v.x; p.h[1] = (__bf16)v.y;
            p.h[2] = (__bf16)v.z; p.h[3] = (__bf16)v.w;
            *(uint2*)(dst + (size_t)(k0 + k) * seg.N + n0 + tc4) = p.u;
        }
        return;
    }
    __shared__ __bf16 tile[64][72];
#pragma unroll
    for (int i = 0; i < 4; ++i) {
        int k = i * 16 + tr;
        float4 v = *(const float4*)(src + (size_t)(k0 + k) * seg.N + n0 + tc4);
        tile[k][tc4 + 0] = (__bf16)v.x;
        tile[k][tc4 + 1] = (__bf16)v.y;
        tile[k][tc4 + 2] = (__bf16)v.z;
        tile[k][tc4 + 3] = (__bf16)v.w;
    }
    __syncthreads();
    const int n = t >> 2, q4 = t & 3;
#pragma unroll
    for (int hh = 0; hh < 2; ++hh) {
        int qq = q4 + hh * 4;
        union { __bf16 h[8]; uint4 u; } pk;
#pragma unroll
        for (int j = 0; j < 8; ++j) pk.h[j] = tile[qq * 8 + j][n];
        *(uint4*)(dst + (size_t)(n0 + n) * seg.K + k0 + qq * 8) = pk.u;
    }
}

// ---------------------------------------------------------------------------
// Gate: fp32 logits -> softmax -> top2 -> per-expert pair lists
// ---------------------------------------------------------------------------
__global__ __launch_bounds__(256)
void gate_kernel(const float* __restrict__ x, const float* __restrict__ gw,
                 float* __restrict__ topw, int* __restrict__ pairs,
                 int* __restrict__ cnt)
{
    int tok  = blockIdx.x * 4 + (threadIdx.x >> 6);
    int lane = threadIdx.x & 63;
    float acc[NE];
#pragma unroll
    for (int e = 0; e < NE; ++e) acc[e] = 0.f;
    const float* xr = x + (size_t)tok * H;
    for (int h = lane; h < H; h += 64) {
        float xv = xr[h];
#pragma unroll
        for (int e = 0; e < NE; ++e) acc[e] += xv * gw[e * H + h];
    }
#pragma unroll
    for (int e = 0; e < NE; ++e) {
        float v = acc[e];
        for (int off = 32; off; off >>= 1) v += __shfl_xor(v, off);
        acc[e] = v;
    }
    if (lane == 0) {
        float mx = acc[0];
#pragma unroll
        for (int e = 1; e < NE; ++e) mx = fmaxf(mx, acc[e]);
        float p[NE]; float s = 0.f;
#pragma unroll
        for (int e = 0; e < NE; ++e) { p[e] = __expf(acc[e] - mx); s += p[e]; }
        float inv = 1.f / s;
        int e1 = 0;
#pragma unroll
        for (int e = 1; e < NE; ++e) if (acc[e] > acc[e1]) e1 = e;
        int e2 = -1;
#pragma unroll
        for (int e = 0; e < NE; ++e) {
            if (e == e1) continue;
            if (e2 < 0 || acc[e] > acc[e2]) e2 = e;
        }
        topw[tok * 2 + 0] = p[e1] * inv;
        topw[tok * 2 + 1] = p[e2] * inv;
        int pos1 = atomicAdd(&cnt[e1], 1);
        pairs[e1 * NTOK + pos1] = tok * 2 + 0;
        int pos2 = atomicAdd(&cnt[e2], 1);
        pairs[e2 * NTOK + pos2] = tok * 2 + 1;
    }
}

// ---------------------------------------------------------------------------
// Scheduler: compact (expert, m-tile) work list. q[0]=count, q[1..] items.
// item = e | (mtile << 4)
// ---------------------------------------------------------------------------
__global__ void sched_kernel(const int* __restrict__ cnt, int* __restrict__ q)
{
    if (threadIdx.x == 0) {
        int pos = 0;
        for (int e = 0; e < NE; ++e) {
            int tc = (cnt[e] + 127) >> 7;
            for (int i = 0; i < tc; ++i) q[1 + pos++] = e | (i << 4);
        }
        q[0] = pos;
    }
}

// ---------------------------------------------------------------------------
// GU GEMM, queue-based grid:
//   b < 352          : shared tile (128m x 128n), m=b/22, n=b%22
//   b >= 352         : routed tile (128m x 64n): p=(b-352)/22 -> q item, n=(b-352)%22
// C = silu(A@Bg^T) * (A@Bu^T); 16x16x32 bf16 MFMA; global_load_lds staging.
// ---------------------------------------------------------------------------
__global__ __launch_bounds__(256, 2)
void gu_kernel(const __bf16* __restrict__ xb,
               const __bf16* __restrict__ wgT, const __bf16* __restrict__ wuT,
               const __bf16* __restrict__ swgT, const __bf16* __restrict__ swuT,
               __bf16* __restrict__ h_sh, __bf16* __restrict__ h_rt,
               const int* __restrict__ pairs, const int* __restrict__ cnt,
               const int* __restrict__ q)
{
    const int t = threadIdx.x, lane = t & 63;
    const int wid = t >> 6, wm = wid >> 1, wn = wid & 1;
    const int b = blockIdx.x;
    const bool routed = (b >= 352);
    int e = 0, m0, n0, count;
    const __bf16 *Bg, *Bu;
    if (routed) {
        int j = b - 352;
        int p = j / 22, nt = j - p * 22;
        if (p >= q[0]) return;
        int item = q[1 + p];
        e = item & 15;
        m0 = (item >> 4) * 128;
        n0 = nt * 64;
        count = cnt[e];
        Bg = wgT + (size_t)e * NI * H;
        Bu = wuT + (size_t)e * NI * H;
    } else {
        int mt = b / 22, nt = b - mt * 22;
        m0 = mt * 128; n0 = nt * 128; count = NTOK;
        Bg = swgT; Bu = swuT;
    }

    __shared__ __align__(16) __bf16 At[128 * 32], Btg[128 * 32], Btu[128 * 32];
    __shared__ int tile_pid[128];
    if (t < 128) {
        int jj = m0 + t;
        tile_pid[t] = routed ? ((jj < count) ? pairs[e * NTOK + jj] : -1) : jj;
    }
    __syncthreads();

    const int r = t >> 2, c = t & 3;
    size_t ar0, ar1;
    if (routed) {
        int p0 = tile_pid[r];      if (p0 < 0) p0 = 0;
        int p1 = tile_pid[r + 64]; if (p1 < 0) p1 = 0;
        ar0 = (size_t)(p0 >> 1); ar1 = (size_t)(p1 >> 1);
    } else {
        ar0 = (size_t)(m0 + r); ar1 = (size_t)(m0 + r + 64);
    }
    const __bf16* a0 = xb + ar0 * H + c * 8;
    const __bf16* a1 = xb + ar1 * H + c * 8;
    const __bf16* g0 = Bg + (size_t)(n0 + r) * H + c * 8;
    const __bf16* u0 = Bu + (size_t)(n0 + r) * H + c * 8;
    const __bf16* g1 = Bg + (size_t)(n0 + r + 64) * H + c * 8;   // shared only
    const __bf16* u1 = Bu + (size_t)(n0 + r + 64) * H + c * 8;   // shared only
    __bf16* lA0 = At  + t * 8;  __bf16* lA1 = At  + (256 + t) * 8;
    __bf16* lG0 = Btg + t * 8;  __bf16* lG1 = Btg + (256 + t) * 8;
    __bf16* lU0 = Btu + t * 8;  __bf16* lU1 = Btu + (256 + t) * 8;

    f32x4 accg[4][4] = {};
    f32x4 accu[4][4] = {};

    for (int k0 = 0; k0 < H; k0 += 32) {
        __syncthreads();
        ASYNC16(a0 + k0, lA0); ASYNC16(a1 + k0, lA1);
        ASYNC16(g0 + k0, lG0); ASYNC16(u0 + k0, lU0);
        if (!routed) { ASYNC16(g1 + k0, lG1); ASYNC16(u1 + k0, lU1); }
        __syncthreads();
        bf16x8 a[4];
#pragma unroll
        for (int mi = 0; mi < 4; ++mi)
            a[mi] = *(const bf16x8*)(At + (wm * 64 + mi * 16 + (lane & 15)) * 32 + (lane >> 4) * 8);
        if (routed) {
#pragma unroll
            for (int ni = 0; ni < 2; ++ni) {
                bf16x8 bg = *(const bf16x8*)(Btg + (wn * 32 + ni * 16 + (lane & 15)) * 32 + (lane >> 4) * 8);
                bf16x8 bu = *(const bf16x8*)(Btu + (wn * 32 + ni * 16 + (lane & 15)) * 32 + (lane >> 4) * 8);
#pragma unroll
                for (int mi = 0; mi < 4; ++mi) {
                    accg[mi][ni] = __builtin_amdgcn_mfma_f32_16x16x32_bf16(a[mi], bg, accg[mi][ni], 0, 0, 0);
                    accu[mi][ni] = __builtin_amdgcn_mfma_f32_16x16x32_bf16(a[mi], bu, accu[mi][ni], 0, 0, 0);
                }
            }
        } else {
#pragma unroll
            for (int ni = 0; ni < 4; ++ni) {
                bf16x8 bg = *(const bf16x8*)(Btg + (wn * 64 + ni * 16 + (lane & 15)) * 32 + (lane >> 4) * 8);
                bf16x8 bu = *(const bf16x8*)(Btu + (wn * 64 + ni * 16 + (lane & 15)) * 32 + (lane >> 4) * 8);
#pragma unroll
                for (int mi = 0; mi < 4; ++mi) {
                    accg[mi][ni] = __builtin_amdgcn_mfma_f32_16x16x32_bf16(a[mi], bg, accg[mi][ni], 0, 0, 0);
                    accu[mi][ni] = __builtin_amdgcn_mfma_f32_16x16x32_bf16(a[mi], bu, accu[mi][ni], 0, 0, 0);
                }
            }
        }
    }

    const int nis = routed ? 2 : 4;
    const int wnw = routed ? 32 : 64;
    __bf16* outp = routed ? h_rt : h_sh;
    const int ldO = routed ? NI : NIS;
#pragma unroll
    for (int mi = 0; mi < 4; ++mi) {
#pragma unroll
        for (int rr = 0; rr < 4; ++rr) {
            int row = wm * 64 + mi * 16 + (lane >> 4) * 4 + rr;
            int pid = tile_pid[row];
            if (routed && pid < 0) continue;
            size_t orow = routed ? (size_t)pid : (size_t)(m0 + row);
            for (int ni = 0; ni < nis; ++ni) {
                int col = n0 + wn * wnw + ni * 16 + (lane & 15);
                float g = accg[mi][ni][rr];
                float u = accu[mi][ni][rr];
                float hv = g / (1.f + __expf(-g)) * u;
                outp[orow * (size_t)ldO + col] = (__bf16)hv;
            }
        }
    }
}

// ---------------------------------------------------------------------------
// Down GEMM, queue-based, atomic epilogue into zeroed d_out:
//   b < 512  : shared split-K: kh=b>>8, m=(b&255)>>4, n=b&15  (K half = NI)
//   b >= 512 : routed: p=(b-512)>>4 -> q item, n=(b-512)&15
// ---------------------------------------------------------------------------
__global__ __launch_bounds__(256, 2)
void down_kernel(const __bf16* __restrict__ h_sh, const __bf16* __restrict__ h_rt,
                 const __bf16* __restrict__ swdT, const __bf16* __restrict__ wdT,
                 float* __restrict__ out,
                 const int* __restrict__ pairs, const int* __restrict__ cnt,
                 const float* __restrict__ topw, const int* __restrict__ q)
{
    const int t = threadIdx.x, lane = t & 63;
    const int wid = t >> 6, wm = wid >> 1, wn = wid & 1;
    const int b = blockIdx.x;
    const bool routed = (b >= 512);
    int e = 0, m0, n0, koff = 0, count, lda;
    const __bf16 *A, *B;
    if (routed) {
        int j = b - 512;
        int p = j >> 4, nt = j & 15;
        if (p >= q[0]) return;
        int item = q[1 + p];
        e = item & 15;
        m0 = (item >> 4) * 128; n0 = nt * 128;
        count = cnt[e];
        A = h_rt; lda = NI;
        B = wdT + (size_t)e * H * NI;
    } else {
        int kh = b >> 8, rem = b & 255;
        n0 = (rem & 15) * 128; m0 = (rem >> 4) * 128;
        koff = kh * NI; count = NTOK;
        A = h_sh; lda = NIS; B = swdT;
    }

    __shared__ __align__(16) __bf16 At[128 * 32], Bt[128 * 32];
    __shared__ int tile_pid[128];
    if (t < 128) {
        int jj = m0 + t;
        tile_pid[t] = routed ? ((jj < count) ? pairs[e * NTOK + jj] : -1) : jj;
    }
    __syncthreads();

    const int r = t >> 2, c = t & 3;
    size_t ar0, ar1;
    if (routed) {
        int p0 = tile_pid[r];      if (p0 < 0) p0 = 0;
        int p1 = tile_pid[r + 64]; if (p1 < 0) p1 = 0;
        ar0 = (size_t)p0; ar1 = (size_t)p1;
    } else {
        ar0 = (size_t)(m0 + r); ar1 = (size_t)(m0 + r + 64);
    }
    const __bf16* a0 = A + ar0 * lda + koff + c * 8;
    const __bf16* a1 = A + ar1 * lda + koff + c * 8;
    const __bf16* b0 = B + (size_t)(n0 + r) * lda + koff + c * 8;
    const __bf16* b1 = B + (size_t)(n0 + r + 64) * lda + koff + c * 8;
    __bf16* lA0 = At + t * 8;  __bf16* lA1 = At + (256 + t) * 8;
    __bf16* lB0 = Bt + t * 8;  __bf16* lB1 = Bt + (256 + t) * 8;

    f32x4 acc[4][4] = {};

    for (int k0 = 0; k0 < NI; k0 += 32) {
        __syncthreads();
        ASYNC16(a0 + k0, lA0); ASYNC16(a1 + k0, lA1);
        ASYNC16(b0 + k0, lB0); ASYNC16(b1 + k0, lB1);
        __syncthreads();
        bf16x8 a[4];
#pragma unroll
        for (int mi = 0; mi < 4; ++mi)
            a[mi] = *(const bf16x8*)(At + (wm * 64 + mi * 16 + (lane & 15)) * 32 + (lane >> 4) * 8);
#pragma unroll
        for (int ni = 0; ni < 4; ++ni) {
            bf16x8 bb = *(const bf16x8*)(Bt + (wn * 64 + ni * 16 + (lane & 15)) * 32 + (lane >> 4) * 8);
#pragma unroll
            for (int mi = 0; mi < 4; ++mi)
                acc[mi][ni] = __builtin_amdgcn_mfma_f32_16x16x32_bf16(a[mi], bb, acc[mi][ni], 0, 0, 0);
        }
    }

#pragma unroll
    for (int mi = 0; mi < 4; ++mi) {
#pragma unroll
        for (int rr = 0; rr < 4; ++rr) {
            int row = wm * 64 + mi * 16 + (lane >> 4) * 4 + rr;
            int pid = tile_pid[row];
            if (routed && pid < 0) continue;
            size_t tok; float w;
            if (routed) { tok = (size_t)(pid >> 1); w = topw[pid]; }
            else        { tok = (size_t)(m0 + row); w = 1.f; }
#pragma unroll
            for (int ni = 0; ni < 4; ++ni) {
                int col = n0 + wn * 64 + ni * 16 + (lane & 15);
                atomicAdd(out + tok * H + col, w * acc[mi][ni][rr]);
            }
        }
    }
}

// ---------------------------------------------------------------------------
static void add_seg(CvtArgs& a, int& nb, const float* s, __bf16* d,
                    int K, int N, int nmat, int trans)
{
    CvtSeg sg;
    sg.src = s; sg.dst = d; sg.K = K; sg.N = N;
    sg.ntx = N / 64;
    sg.tiles_per_mat = (N / 64) * (K / 64);
    sg.trans = trans;
    sg.count = sg.tiles_per_mat * nmat;
    a.base[a.nseg] = nb;
    a.s[a.nseg++] = sg;
    nb += sg.count;
    a.base[a.nseg] = nb;
}

extern "C" void kernel_launch(void* const* d_in, const int* in_sizes, int n_in,
                              void* d_out, int out_size, void* d_ws, size_t ws_size,
                              hipStream_t stream)
{
    const float* x       = (const float*)d_in[0];
    const float* gate_w  = (const float*)d_in[1];
    const float* w_gate  = (const float*)d_in[2];
    const float* w_up    = (const float*)d_in[3];
    const float* w_down  = (const float*)d_in[4];
    const float* sw_gate = (const float*)d_in[5];
    const float* sw_up   = (const float*)d_in[6];
    const float* sw_down = (const float*)d_in[7];

    char*   ws    = (char*)d_ws;
    float*  topw  = (float*)ws;                     // 16 KB
    int*    cnt   = (int*)(ws + 16384);             // 8 ints
    int*    q     = (int*)(ws + 16512);             // 1 + 64 ints
    int*    pairs = (int*)(ws + 17408);             // 64 KB
    __bf16* xb    = (__bf16*)(ws + 131072);
    __bf16* h_sh  = (__bf16*)(ws + 8519680);
    __bf16* h_rt  = (__bf16*)(ws + 20054016);
    __bf16* swgT  = (__bf16*)(ws + 31588352);
    __bf16* swuT  = (__bf16*)(ws + 43122688);
    __bf16* swdT  = (__bf16*)(ws + 54657024);
    __bf16* wgT   = (__bf16*)(ws + 66191360);
    __bf16* wuT   = (__bf16*)(ws + 112328704);
    const bool bigws = ws_size >= (size_t)158466048 + 46137344;
    __bf16* wdT   = bigws ? (__bf16*)(ws + 158466048) : wgT;  // alias fallback

    hipMemsetAsync(cnt, 0, NE * sizeof(int), stream);
    hipMemsetAsync(d_out, 0, (size_t)NTOK * H * sizeof(float), stream);

    gate_kernel<<<NTOK / 4, 256, 0, stream>>>(x, gate_w, topw, pairs, cnt);
    sched_kernel<<<1, 64, 0, stream>>>(cnt, q);

    // one merged conversion launch (x copy + all weight transposes)
    CvtArgs ca; ca.nseg = 0; int nb = 0;
    add_seg(ca, nb, x,       xb,   NTOK, H,  1,  0);
    add_seg(ca, nb, sw_gate, swgT, H,  NIS,  1,  1);
    add_seg(ca, nb, sw_up,   swuT, H,  NIS,  1,  1);
    add_seg(ca, nb, sw_down, swdT, NIS, H,   1,  1);
    add_seg(ca, nb, w_gate,  wgT,  H,  NI,   NE, 1);
    add_seg(ca, nb, w_up,    wuT,  H,  NI,   NE, 1);
    if (bigws) add_seg(ca, nb, w_down, wdT, NI, H, NE, 1);
    cvt_all_kernel<<<nb, 256, 0, stream>>>(ca);

    // GU: 352 shared (128x128) + up to 880 routed (128x64)
    gu_kernel<<<352 + 22 * 40, 256, 0, stream>>>(
        xb, wgT, wuT, swgT, swuT, h_sh, h_rt, pairs, cnt, q);

    if (!bigws) {   // late w_down conversion into the region gu just freed
        CvtArgs cb; cb.nseg = 0; int nb2 = 0;
        add_seg(cb, nb2, w_down, wdT, NI, H, NE, 1);
        cvt_all_kernel<<<nb2, 256, 0, stream>>>(cb);
    }

    // Down: 512 shared split-K + up to 640 routed, atomics into zeroed d_out
    down_kernel<<<512 + 16 * 40, 256, 0, stream>>>(
        h_sh, h_rt, swdT, wdT, (float*)d_out, pairs, cnt, topw, q);
}